// Round 16
// baseline (185.793 us; speedup 1.0000x reference)
//
#include <hip/hip_runtime.h>
#include <math.h>

#define NG    1024
#define NPG   64
#define EPG   512
#define NEDGE 524288
#define DINF  64

typedef __attribute__((ext_vector_type(8))) short short8b;     // 8 x bf16
typedef __attribute__((ext_vector_type(4))) short short4b;     // 4 x bf16
typedef __attribute__((ext_vector_type(8))) _Float16 f16x8;
typedef __attribute__((ext_vector_type(4))) _Float16 f16x4;
typedef __attribute__((ext_vector_type(4))) float f32x4;

__device__ __forceinline__ float gelu_exact(float v) {
    return 0.5f * v * (1.0f + erff(v * 0.70710678118654752440f));
}
__device__ __forceinline__ void split_bf16(float v, short& hi, short& lo) {
    unsigned u = __builtin_bit_cast(unsigned, v);
    hi = (short)(u >> 16);
    float hif = __builtin_bit_cast(float, u & 0xffff0000u);
    lo = (short)(__builtin_bit_cast(unsigned, v - hif) >> 16);
}

// ---- LDS layouts (element index), 8-elem(16B)-chunk XOR-swizzled ----
__device__ __forceinline__ int hidx(int m, int k) {   // h[64 node][128 feat] bf16-pair
    return m * 128 + (((k >> 3) ^ (m & 15)) << 3) + (k & 7);
}
__device__ __forceinline__ int tidx(int f, int m) {   // hwT[128 feat][64 node] f16-pair
    return f * 64 + (((m >> 3) ^ (f & 7)) << 3) + (m & 7);
}
__device__ __forceinline__ int sidx(int d, int k) {   // S[64 dst][64 src] f16
    return d * 64 + (((k >> 3) ^ (d & 7)) << 3) + (k & 7);
}

// One GCN layer: bf16-pair GEMM (3 products, 1 accumulator) ->
// hwT f16-pair (unscaled lo, 1 accumulator AGG) -> gelu -> bf16-pair h.
__device__ __forceinline__ void gcn_layer_mix(
    short* Hh, short* Hl, const _Float16* Sf,
    const short* __restrict__ Wh, const short* __restrict__ Wl,
    const float* __restrict__ bb, int t)
{
    const int l15 = t & 15, lk = (t >> 4) & 3, w = t >> 6;
    const int nb = w * 32;          // wave owns feats [nb, nb+32)

    // ---- GEMM: hw[node][feat] = h @ W  (M=64, N=128 (32/wave), K=128) ----
    f32x4 acc[4][2];
#pragma unroll
    for (int mt = 0; mt < 4; ++mt)
#pragma unroll
        for (int nt = 0; nt < 2; ++nt) acc[mt][nt] = (f32x4){0.f, 0.f, 0.f, 0.f};

    __builtin_amdgcn_s_setprio(1);
#pragma unroll
    for (int k0 = 0; k0 < 128; k0 += 32) {
        const int kk = k0 + lk * 8;
        short8b bh[2], bl[2];
#pragma unroll
        for (int nt = 0; nt < 2; ++nt) {
            int n = nb + nt * 16 + l15;
            bh[nt] = *(const short8b*)&Wh[n * 128 + kk];
            bl[nt] = *(const short8b*)&Wl[n * 128 + kk];
        }
#pragma unroll
        for (int mt = 0; mt < 4; ++mt) {
            short8b ah = *(const short8b*)&Hh[hidx(mt * 16 + l15, kk)];
            short8b al = *(const short8b*)&Hl[hidx(mt * 16 + l15, kk)];
#pragma unroll
            for (int nt = 0; nt < 2; ++nt) {
                acc[mt][nt] = __builtin_amdgcn_mfma_f32_16x16x32_bf16(ah, bh[nt], acc[mt][nt], 0, 0, 0);
                acc[mt][nt] = __builtin_amdgcn_mfma_f32_16x16x32_bf16(ah, bl[nt], acc[mt][nt], 0, 0, 0);
                acc[mt][nt] = __builtin_amdgcn_mfma_f32_16x16x32_bf16(al, bh[nt], acc[mt][nt], 0, 0, 0);
            }
        }
    }
    __builtin_amdgcn_s_setprio(0);
    __syncthreads();   // all waves done reading h; region becomes hwT (f16)

    _Float16* Th = (_Float16*)Hh;
    _Float16* Tl = (_Float16*)Hl;

    // ---- hwT[feat][node] f16 pair (lo unscaled), b64 writes ----
#pragma unroll
    for (int mt = 0; mt < 4; ++mt)
#pragma unroll
        for (int nt = 0; nt < 2; ++nt) {
            int f = nb + nt * 16 + l15;
            f16x4 h4, l4;
#pragma unroll
            for (int r = 0; r < 4; ++r) {
                float v = acc[mt][nt][r];
                _Float16 hi = (_Float16)v;
                _Float16 lo = (_Float16)(v - (float)hi);
                h4[r] = hi; l4[r] = lo;
            }
            int id = tidx(f, mt * 16 + lk * 4);
            *(f16x4*)&Th[id] = h4;
            *(f16x4*)&Tl[id] = l4;
        }

    // ---- AGG: D2[feat][dst] = hwT @ S^T (M=128 (32/wave), N=64, K=64) ----
    f32x4 a2[2][4];
#pragma unroll
    for (int mt = 0; mt < 2; ++mt)
#pragma unroll
        for (int nt = 0; nt < 4; ++nt) a2[mt][nt] = (f32x4){0.f, 0.f, 0.f, 0.f};

    __builtin_amdgcn_s_setprio(1);
#pragma unroll
    for (int k0 = 0; k0 < 64; k0 += 32) {
        const int kk = k0 + lk * 8;
        f16x8 sb[4];
#pragma unroll
        for (int nt = 0; nt < 4; ++nt)
            sb[nt] = *(const f16x8*)&Sf[sidx(nt * 16 + l15, kk)];
#pragma unroll
        for (int mt = 0; mt < 2; ++mt) {
            int f = nb + mt * 16 + l15;
            f16x8 ah = *(const f16x8*)&Th[tidx(f, kk)];
            f16x8 al = *(const f16x8*)&Tl[tidx(f, kk)];
#pragma unroll
            for (int nt = 0; nt < 4; ++nt) {
                a2[mt][nt] = __builtin_amdgcn_mfma_f32_16x16x32_f16(ah, sb[nt], a2[mt][nt], 0, 0, 0);
                a2[mt][nt] = __builtin_amdgcn_mfma_f32_16x16x32_f16(al, sb[nt], a2[mt][nt], 0, 0, 0);
            }
        }
    }
    __builtin_amdgcn_s_setprio(0);
    __syncthreads();   // all hwT/S reads done; region becomes new h (bf16)

    // ---- new h[node][feat] = gelu(D2^T + b[feat]); b64 (4 consecutive feats) ----
#pragma unroll
    for (int mt = 0; mt < 2; ++mt) {
        int f0 = nb + mt * 16 + lk * 4;
        float4 bv = *(const float4*)&bb[f0];
#pragma unroll
        for (int nt = 0; nt < 4; ++nt) {
            int dst = nt * 16 + l15;
            short4b h4, l4;
            float v0 = gelu_exact(a2[mt][nt][0] + bv.x);
            float v1 = gelu_exact(a2[mt][nt][1] + bv.y);
            float v2 = gelu_exact(a2[mt][nt][2] + bv.z);
            float v3 = gelu_exact(a2[mt][nt][3] + bv.w);
            short hi, lo;
            split_bf16(v0, hi, lo); h4[0] = hi; l4[0] = lo;
            split_bf16(v1, hi, lo); h4[1] = hi; l4[1] = lo;
            split_bf16(v2, hi, lo); h4[2] = hi; l4[2] = lo;
            split_bf16(v3, hi, lo); h4[3] = hi; l4[3] = lo;
            int id = hidx(dst, f0);
            *(short4b*)&Hh[id] = h4;
            *(short4b*)&Hl[id] = l4;
        }
    }
    __syncthreads();
}

// Latency-minimized GRU step on pre-scaled gate constants.
__device__ __forceinline__ float gru_step(float h, float4 gi,
    float wrc, float wzc, float wnc2, float bnc2)
{
    float ur = fmaf(h, wrc, gi.x);
    float uz = fmaf(h, wzc, gi.y);
    float hn = fmaf(h, wnc2, bnc2);
    float rr = __builtin_amdgcn_rcpf(1.f + __builtin_amdgcn_exp2f(ur));
    float zz = __builtin_amdgcn_rcpf(1.f + __builtin_amdgcn_exp2f(uz));
    float xn = fmaf(rr, hn, gi.z);
    float qq = __builtin_amdgcn_rcpf(1.f + __builtin_amdgcn_exp2f(xn));
    float A = 1.f - zz;
    float C = fmaf(zz, h, A);
    return fmaf(qq, -2.f * A, C);   // (1-2q)(1-z) + z*h
}

__global__ __launch_bounds__(256, 4) void fused_graph(
    const float* __restrict__ x, const float* __restrict__ emb,
    const float* __restrict__ b1, const float* __restrict__ b2,
    const float* __restrict__ b3, const float* __restrict__ fcb,
    const float* __restrict__ Wih, const float* __restrict__ bih,
    const float* __restrict__ Whh, const float* __restrict__ bhh,
    const float* __restrict__ init_hs,
    const int* __restrict__ ei, const short* __restrict__ wt,
    float* __restrict__ out)
{
    // 40960 B total = 4 blocks/CU exactly; grid 1024 = one full round.
    // Sf region [32768,40960) is dead after layer-3 AGG -> reused as gl[512] float4.
    __shared__ __align__(16) char LDS[40960];
    short* Hh = (short*)LDS;
    short* Hl = (short*)(LDS + 16384);
    float* S32 = (float*)LDS;                     // [0, 16384)
    int* cnt = (int*)(LDS + 16384);               // 256 B
    float* dinvL = (float*)(LDS + 16640);         // 256 B
    float* fcout = (float*)LDS;                   // [0, 17408)
    float* wihL = (float*)(LDS + 17408);          // 768 B
    _Float16* Sf = (_Float16*)(LDS + 32768);      // 8192 B
    float4* gl = (float4*)(LDS + 32768);          // gi constants after Sf is dead

    const int g = blockIdx.x;
    const int t = threadIdx.x;

    // ---- zero S32 + cnt ----
#pragma unroll
    for (int j = 0; j < 16; ++j) S32[t + 256 * j] = 0.f;
    if (t < NPG) cnt[t] = 0;
    __syncthreads();

    // ---- edges (2/thread, live in regs all kernel) + degree count ----
    const int gb = g * NPG;
    const int i0 = t, i1 = t + 256;
    const int r0 = ei[g * EPG + i0] - gb, c0 = ei[NEDGE + g * EPG + i0] - gb;
    const int r1 = ei[g * EPG + i1] - gb, c1 = ei[NEDGE + g * EPG + i1] - gb;
    atomicAdd(&cnt[c0], 1);
    atomicAdd(&cnt[c1], 1);
    __syncthreads();

    if (t < NPG) dinvL[t] = rsqrtf((float)(cnt[t] + 1));   // +1 self loop
    __syncthreads();

    // ---- dense normalized adjacency S32[dst][src] (duplicates accumulate) ----
    atomicAdd(&S32[c0 * 64 + r0], dinvL[r0] * dinvL[c0]);
    atomicAdd(&S32[c1 * 64 + r1], dinvL[r1] * dinvL[c1]);
    if (t < NPG) atomicAdd(&S32[t * 64 + t], dinvL[t] * dinvL[t]);
    __syncthreads();

    // ---- S32 -> Sf16 (separate region), b128 writes ----
#pragma unroll
    for (int cp = 0; cp < 2; ++cp) {
        int cid = 2 * t + cp, d = cid >> 3, kc = cid & 7;
        f16x8 s8;
#pragma unroll
        for (int j = 0; j < 8; ++j) s8[j] = (_Float16)S32[d * 64 + kc * 8 + j];
        *(f16x8*)&Sf[sidx(d, kc * 8)] = s8;
    }
    __syncthreads();   // S32 reads done; Ubuf becomes H

    // ---- stage h0 = [feat | emb[nid]] as bf16 pair, b128 writes ----
#pragma unroll
    for (int rep = 0; rep < 4; ++rep) {
        int id = t + rep * 256;              // 1024 chunk tasks: n(64) x kc(16)
        int n = id >> 4, kc = id & 15;
        const float* xr = x + (g * NPG + n) * 65;
        float v[8];
        if (kc < 8) {
#pragma unroll
            for (int j = 0; j < 8; ++j) v[j] = xr[kc * 8 + j];
        } else {
            int nid = (int)xr[64];
            const float4* e4 = (const float4*)&emb[nid * DINF + (kc - 8) * 8];
            float4 va = e4[0], vb = e4[1];
            v[0] = va.x; v[1] = va.y; v[2] = va.z; v[3] = va.w;
            v[4] = vb.x; v[5] = vb.y; v[6] = vb.z; v[7] = vb.w;
        }
        short8b h8, l8;
#pragma unroll
        for (int j = 0; j < 8; ++j) {
            short hi, lo; split_bf16(v[j], hi, lo);
            h8[j] = hi; l8[j] = lo;
        }
        int idd = hidx(n, kc * 8);
        *(short8b*)&Hh[idd] = h8;
        *(short8b*)&Hl[idd] = l8;
    }
    __syncthreads();

    gcn_layer_mix(Hh, Hl, Sf, wt,         wt + 16384, b1, t);
    gcn_layer_mix(Hh, Hl, Sf, wt + 32768, wt + 49152, b2, t);
    gcn_layer_mix(Hh, Hl, Sf, wt + 65536, wt + 81920, b3, t);

    // ---- fc: gelu(h3 @ fcW + fcb) -> fcout[64][68] fp32 ----
    {
        const short* Fh = wt + 98304;
        const short* Fl = wt + 106496;
        const int l15 = t & 15, lk = (t >> 4) & 3, w = t >> 6;
        const int nb2 = w * 16;
        f32x4 fa[4];
#pragma unroll
        for (int mt = 0; mt < 4; ++mt) fa[mt] = (f32x4){0.f, 0.f, 0.f, 0.f};
        __builtin_amdgcn_s_setprio(1);
#pragma unroll
        for (int k0 = 0; k0 < 128; k0 += 32) {
            const int kk = k0 + lk * 8;
            int n = nb2 + l15;
            short8b bhf = *(const short8b*)&Fh[n * 128 + kk];
            short8b blf = *(const short8b*)&Fl[n * 128 + kk];
#pragma unroll
            for (int mt = 0; mt < 4; ++mt) {
                short8b ah = *(const short8b*)&Hh[hidx(mt * 16 + l15, kk)];
                short8b al = *(const short8b*)&Hl[hidx(mt * 16 + l15, kk)];
                fa[mt] = __builtin_amdgcn_mfma_f32_16x16x32_bf16(ah, bhf, fa[mt], 0, 0, 0);
                fa[mt] = __builtin_amdgcn_mfma_f32_16x16x32_bf16(ah, blf, fa[mt], 0, 0, 0);
                fa[mt] = __builtin_amdgcn_mfma_f32_16x16x32_bf16(al, bhf, fa[mt], 0, 0, 0);
            }
        }
        __builtin_amdgcn_s_setprio(0);
        __syncthreads();   // h3 reads done; region becomes fcout + wih
        int n = nb2 + l15;
        float fb = fcb[n];
#pragma unroll
        for (int mt = 0; mt < 4; ++mt)
#pragma unroll
            for (int r = 0; r < 4; ++r) {
                int m = mt * 16 + lk * 4 + r;
                fcout[m * 68 + n] = gelu_exact(fa[mt][r] + fb);
            }
        if (t < 3 * DINF) wihL[t] = Wih[t];
    }
    __syncthreads();   // fcout + wih ready; Sf dead -> gl region live

    // ---- per-edge GRU gate constants -> gl (LDS), pre-scaled ----
    {
        const float L2E = 1.4426950408889634f;
        const float bi0 = bih[0], bi1 = bih[1], bi2 = bih[2];
        const float bh0 = bhh[0], bh1 = bhh[1];
        const float4* hra = (const float4*)&fcout[r0 * 68];
        const float4* hca = (const float4*)&fcout[c0 * 68];
        const float4* hrb = (const float4*)&fcout[r1 * 68];
        const float4* hcb = (const float4*)&fcout[c1 * 68];
        float4 ar0 = {0,0,0,0}, az0 = {0,0,0,0}, an0 = {0,0,0,0};
        float4 ar1 = {0,0,0,0}, az1 = {0,0,0,0}, an1 = {0,0,0,0};
#pragma unroll
        for (int i = 0; i < 16; ++i) {
            float4 wr = *(const float4*)&wihL[i * 4];
            float4 wz = *(const float4*)&wihL[DINF + i * 4];
            float4 wn = *(const float4*)&wihL[2 * DINF + i * 4];
            float4 pa = hra[i], qa = hca[i], pb = hrb[i], qb = hcb[i];
            float4 x0, x1;
            x0.x = 0.5f * (pa.x + qa.x); x0.y = 0.5f * (pa.y + qa.y);
            x0.z = 0.5f * (pa.z + qa.z); x0.w = 0.5f * (pa.w + qa.w);
            x1.x = 0.5f * (pb.x + qb.x); x1.y = 0.5f * (pb.y + qb.y);
            x1.z = 0.5f * (pb.z + qb.z); x1.w = 0.5f * (pb.w + qb.w);
            ar0.x = fmaf(x0.x, wr.x, ar0.x); ar0.y = fmaf(x0.y, wr.y, ar0.y);
            ar0.z = fmaf(x0.z, wr.z, ar0.z); ar0.w = fmaf(x0.w, wr.w, ar0.w);
            az0.x = fmaf(x0.x, wz.x, az0.x); az0.y = fmaf(x0.y, wz.y, az0.y);
            az0.z = fmaf(x0.z, wz.z, az0.z); az0.w = fmaf(x0.w, wz.w, az0.w);
            an0.x = fmaf(x0.x, wn.x, an0.x); an0.y = fmaf(x0.y, wn.y, an0.y);
            an0.z = fmaf(x0.z, wn.z, an0.z); an0.w = fmaf(x0.w, wn.w, an0.w);
            ar1.x = fmaf(x1.x, wr.x, ar1.x); ar1.y = fmaf(x1.y, wr.y, ar1.y);
            ar1.z = fmaf(x1.z, wr.z, ar1.z); ar1.w = fmaf(x1.w, wr.w, ar1.w);
            az1.x = fmaf(x1.x, wz.x, az1.x); az1.y = fmaf(x1.y, wz.y, az1.y);
            az1.z = fmaf(x1.z, wz.z, az1.z); az1.w = fmaf(x1.w, wz.w, az1.w);
            an1.x = fmaf(x1.x, wn.x, an1.x); an1.y = fmaf(x1.y, wn.y, an1.y);
            an1.z = fmaf(x1.z, wn.z, an1.z); an1.w = fmaf(x1.w, wn.w, an1.w);
        }
        const float L2Ec = L2E;
        float a0 = (ar0.x + ar0.y) + (ar0.z + ar0.w);
        float a1 = (az0.x + az0.y) + (az0.z + az0.w);
        float a2v = (an0.x + an0.y) + (an0.z + an0.w);
        gl[i0] = make_float4(-L2Ec * (a0 + bi0 + bh0),
                             -L2Ec * (a1 + bi1 + bh1),
                             2.f * L2Ec * (a2v + bi2), 0.f);
        a0 = (ar1.x + ar1.y) + (ar1.z + ar1.w);
        a1 = (az1.x + az1.y) + (az1.z + az1.w);
        a2v = (an1.x + an1.y) + (an1.z + an1.w);
        gl[i1] = make_float4(-L2Ec * (a0 + bi0 + bh0),
                             -L2Ec * (a1 + bi1 + bh1),
                             2.f * L2Ec * (a2v + bi2), 0.f);
    }
    __syncthreads();

    // ---- GRU scan for this graph (lane 0), gi from LDS, static indexing ----
    if (t == 0) {
        const float L2E = 1.4426950408889634f;
        const float wrc = -L2E * Whh[0];
        const float wzc = -L2E * Whh[1];
        const float wnc2 = 2.f * L2E * Whh[2];
        const float bnc2 = 2.f * L2E * bhh[2];
        float h = init_hs[0];
        float ssum = 0.f, lastval = 0.f, firstval = 0.f;
        int lastidx = -1;
        float* flat = out + NG + (size_t)g * EPG;

        for (int tt = 0; tt < EPG; tt += 4) {
            float4 q0 = gl[tt + 0];
            float4 q1 = gl[tt + 1];
            float4 q2 = gl[tt + 2];
            float4 q3 = gl[tt + 3];
            float4 hq;
            h = gru_step(h, q0, wrc, wzc, wnc2, bnc2); hq.x = h;
            h = gru_step(h, q1, wrc, wzc, wnc2, bnc2); hq.y = h;
            h = gru_step(h, q2, wrc, wzc, wnc2, bnc2); hq.z = h;
            h = gru_step(h, q3, wrc, wzc, wnc2, bnc2); hq.w = h;
            *(float4*)&flat[tt] = hq;
            if (tt == 0) firstval = hq.x;
            ssum += ((hq.x + hq.y) + (hq.z + hq.w));
            if (hq.x != 0.f) { lastidx = tt;     lastval = hq.x; }
            if (hq.y != 0.f) { lastidx = tt + 1; lastval = hq.y; }
            if (hq.z != 0.f) { lastidx = tt + 2; lastval = hq.z; }
            if (hq.w != 0.f) { lastidx = tt + 3; lastval = hq.w; }
        }
        out[g] = (ssum > 0.f && lastidx >= 0) ? lastval : firstval;
    }
}

// ---- weight pre-transpose/convert: W[k][n] -> Wt_hi/lo[n][k] bf16 ----
__global__ __launch_bounds__(256) void conv_weights(
    const float* __restrict__ W1, const float* __restrict__ W2,
    const float* __restrict__ W3, const float* __restrict__ fcW,
    short* __restrict__ wt)
{
    int tid = blockIdx.x * 256 + threadIdx.x;
    if (tid < 49152) {
        int L = tid >> 14, e = tid & 16383;
        const float* W = (L == 0) ? W1 : (L == 1) ? W2 : W3;
        float v = W[e];                  // e = k*128 + n
        int k = e >> 7, n = e & 127;
        short hi, lo; split_bf16(v, hi, lo);
        wt[L * 32768 + n * 128 + k] = hi;
        wt[L * 32768 + 16384 + n * 128 + k] = lo;
    } else if (tid < 57344) {
        int e = tid - 49152;
        float v = fcW[e];                // e = k*64 + n
        int k = e >> 6, n = e & 63;
        short hi, lo; split_bf16(v, hi, lo);
        wt[98304 + n * 128 + k] = hi;
        wt[106496 + n * 128 + k] = lo;
    }
}

extern "C" void kernel_launch(void* const* d_in, const int* in_sizes, int n_in,
                              void* d_out, int out_size, void* d_ws, size_t ws_size,
                              hipStream_t stream) {
    const float* x    = (const float*)d_in[0];
    const float* emb  = (const float*)d_in[1];
    const float* W1   = (const float*)d_in[2];
    const float* b1   = (const float*)d_in[3];
    const float* W2   = (const float*)d_in[4];
    const float* b2   = (const float*)d_in[5];
    const float* W3   = (const float*)d_in[6];
    const float* b3   = (const float*)d_in[7];
    const float* fcW  = (const float*)d_in[8];
    const float* fcb  = (const float*)d_in[9];
    const float* Wih  = (const float*)d_in[10];
    const float* Whh  = (const float*)d_in[11];
    const float* bih  = (const float*)d_in[12];
    const float* bhh  = (const float*)d_in[13];
    const float* ihs  = (const float*)d_in[14];
    const int*   ei   = (const int*)d_in[15];
    float* out = (float*)d_out;

    short* wt = (short*)d_ws;   // 229376 B of converted weights

    conv_weights<<<dim3(224), dim3(256), 0, stream>>>(W1, W2, W3, fcW, wt);
    fused_graph<<<dim3(NG), dim3(256), 0, stream>>>(
        x, emb, b1, b2, b3, fcb, Wih, bih, Whh, bhh, ihs, ei, wt, out);
}

// Round 17
// 104.813 us; speedup vs baseline: 1.7726x; 1.7726x over previous
//
#include <hip/hip_runtime.h>
#include <math.h>

#define NG    1024
#define NPG   64
#define EPG   512
#define NEDGE 524288
#define DINF  64

typedef __attribute__((ext_vector_type(8))) short short8b;     // 8 x bf16
typedef __attribute__((ext_vector_type(4))) short short4b;     // 4 x bf16
typedef __attribute__((ext_vector_type(8))) _Float16 f16x8;
typedef __attribute__((ext_vector_type(4))) _Float16 f16x4;
typedef __attribute__((ext_vector_type(4))) float f32x4;

__device__ __forceinline__ float gelu_exact(float v) {
    return 0.5f * v * (1.0f + erff(v * 0.70710678118654752440f));
}
__device__ __forceinline__ void split_bf16(float v, short& hi, short& lo) {
    unsigned u = __builtin_bit_cast(unsigned, v);
    hi = (short)(u >> 16);
    float hif = __builtin_bit_cast(float, u & 0xffff0000u);
    lo = (short)(__builtin_bit_cast(unsigned, v - hif) >> 16);
}

// ---- LDS layouts (element index), 8-elem(16B)-chunk XOR-swizzled ----
__device__ __forceinline__ int hidx(int m, int k) {   // h[64 node][128 feat] bf16-pair
    return m * 128 + (((k >> 3) ^ (m & 15)) << 3) + (k & 7);
}
__device__ __forceinline__ int tidx(int f, int m) {   // hwT[128 feat][64 node] f16-pair
    return f * 64 + (((m >> 3) ^ (f & 7)) << 3) + (m & 7);
}
__device__ __forceinline__ int sidx(int d, int k) {   // S[64 dst][64 src] f16
    return d * 64 + (((k >> 3) ^ (d & 7)) << 3) + (k & 7);
}

// One GCN layer: bf16-pair GEMM (3 products, 1 accumulator) ->
// hwT f16-pair (unscaled lo, 1 accumulator AGG) -> gelu -> bf16-pair h.
__device__ __forceinline__ void gcn_layer_mix(
    short* Hh, short* Hl, const _Float16* Sf,
    const short* __restrict__ Wh, const short* __restrict__ Wl,
    const float* __restrict__ bb, int t)
{
    const int l15 = t & 15, lk = (t >> 4) & 3, w = t >> 6;
    const int nb = w * 32;          // wave owns feats [nb, nb+32)

    // ---- GEMM: hw[node][feat] = h @ W  (M=64, N=128 (32/wave), K=128) ----
    f32x4 acc[4][2];
#pragma unroll
    for (int mt = 0; mt < 4; ++mt)
#pragma unroll
        for (int nt = 0; nt < 2; ++nt) acc[mt][nt] = (f32x4){0.f, 0.f, 0.f, 0.f};

    __builtin_amdgcn_s_setprio(1);
#pragma unroll
    for (int k0 = 0; k0 < 128; k0 += 32) {
        const int kk = k0 + lk * 8;
        short8b bh[2], bl[2];
#pragma unroll
        for (int nt = 0; nt < 2; ++nt) {
            int n = nb + nt * 16 + l15;
            bh[nt] = *(const short8b*)&Wh[n * 128 + kk];
            bl[nt] = *(const short8b*)&Wl[n * 128 + kk];
        }
#pragma unroll
        for (int mt = 0; mt < 4; ++mt) {
            short8b ah = *(const short8b*)&Hh[hidx(mt * 16 + l15, kk)];
            short8b al = *(const short8b*)&Hl[hidx(mt * 16 + l15, kk)];
#pragma unroll
            for (int nt = 0; nt < 2; ++nt) {
                acc[mt][nt] = __builtin_amdgcn_mfma_f32_16x16x32_bf16(ah, bh[nt], acc[mt][nt], 0, 0, 0);
                acc[mt][nt] = __builtin_amdgcn_mfma_f32_16x16x32_bf16(ah, bl[nt], acc[mt][nt], 0, 0, 0);
                acc[mt][nt] = __builtin_amdgcn_mfma_f32_16x16x32_bf16(al, bh[nt], acc[mt][nt], 0, 0, 0);
            }
        }
    }
    __builtin_amdgcn_s_setprio(0);
    __syncthreads();   // all waves done reading h; region becomes hwT (f16)

    _Float16* Th = (_Float16*)Hh;
    _Float16* Tl = (_Float16*)Hl;

    // ---- hwT[feat][node] f16 pair (lo unscaled), b64 writes ----
#pragma unroll
    for (int mt = 0; mt < 4; ++mt)
#pragma unroll
        for (int nt = 0; nt < 2; ++nt) {
            int f = nb + nt * 16 + l15;
            f16x4 h4, l4;
#pragma unroll
            for (int r = 0; r < 4; ++r) {
                float v = acc[mt][nt][r];
                _Float16 hi = (_Float16)v;
                _Float16 lo = (_Float16)(v - (float)hi);
                h4[r] = hi; l4[r] = lo;
            }
            int id = tidx(f, mt * 16 + lk * 4);
            *(f16x4*)&Th[id] = h4;
            *(f16x4*)&Tl[id] = l4;
        }

    // ---- AGG: D2[feat][dst] = hwT @ S^T (M=128 (32/wave), N=64, K=64) ----
    f32x4 a2[2][4];
#pragma unroll
    for (int mt = 0; mt < 2; ++mt)
#pragma unroll
        for (int nt = 0; nt < 4; ++nt) a2[mt][nt] = (f32x4){0.f, 0.f, 0.f, 0.f};

    __builtin_amdgcn_s_setprio(1);
#pragma unroll
    for (int k0 = 0; k0 < 64; k0 += 32) {
        const int kk = k0 + lk * 8;
        f16x8 sb[4];
#pragma unroll
        for (int nt = 0; nt < 4; ++nt)
            sb[nt] = *(const f16x8*)&Sf[sidx(nt * 16 + l15, kk)];
#pragma unroll
        for (int mt = 0; mt < 2; ++mt) {
            int f = nb + mt * 16 + l15;
            f16x8 ah = *(const f16x8*)&Th[tidx(f, kk)];
            f16x8 al = *(const f16x8*)&Tl[tidx(f, kk)];
#pragma unroll
            for (int nt = 0; nt < 4; ++nt) {
                a2[mt][nt] = __builtin_amdgcn_mfma_f32_16x16x32_f16(ah, sb[nt], a2[mt][nt], 0, 0, 0);
                a2[mt][nt] = __builtin_amdgcn_mfma_f32_16x16x32_f16(al, sb[nt], a2[mt][nt], 0, 0, 0);
            }
        }
    }
    __builtin_amdgcn_s_setprio(0);
    __syncthreads();   // all hwT/S reads done; region becomes new h (bf16)

    // ---- new h[node][feat] = gelu(D2^T + b[feat]); b64 (4 consecutive feats) ----
#pragma unroll
    for (int mt = 0; mt < 2; ++mt) {
        int f0 = nb + mt * 16 + lk * 4;
        float4 bv = *(const float4*)&bb[f0];
#pragma unroll
        for (int nt = 0; nt < 4; ++nt) {
            int dst = nt * 16 + l15;
            short4b h4, l4;
            float v0 = gelu_exact(a2[mt][nt][0] + bv.x);
            float v1 = gelu_exact(a2[mt][nt][1] + bv.y);
            float v2 = gelu_exact(a2[mt][nt][2] + bv.z);
            float v3 = gelu_exact(a2[mt][nt][3] + bv.w);
            short hi, lo;
            split_bf16(v0, hi, lo); h4[0] = hi; l4[0] = lo;
            split_bf16(v1, hi, lo); h4[1] = hi; l4[1] = lo;
            split_bf16(v2, hi, lo); h4[2] = hi; l4[2] = lo;
            split_bf16(v3, hi, lo); h4[3] = hi; l4[3] = lo;
            int id = hidx(dst, f0);
            *(short4b*)&Hh[id] = h4;
            *(short4b*)&Hl[id] = l4;
        }
    }
    __syncthreads();
}

__global__ __launch_bounds__(256, 4) void fused_graph(
    const float* __restrict__ x, const float* __restrict__ emb,
    const float* __restrict__ b1, const float* __restrict__ b2,
    const float* __restrict__ b3, const float* __restrict__ fcb,
    const float* __restrict__ Wih, const float* __restrict__ bih,
    const float* __restrict__ bhh,
    const int* __restrict__ ei, const short* __restrict__ wt,
    float* __restrict__ grc, float* __restrict__ gzc, float* __restrict__ gnc)
{
    // 40960 B total = 4 blocks/CU exactly; grid 1024 = one full round.
    __shared__ __align__(16) char LDS[40960];
    short* Hh = (short*)LDS;
    short* Hl = (short*)(LDS + 16384);
    float* S32 = (float*)LDS;                     // [0, 16384)
    int* cnt = (int*)(LDS + 16384);               // 256 B
    float* dinvL = (float*)(LDS + 16640);         // 256 B
    float* fcout = (float*)LDS;                   // [0, 17408)
    float* wihL = (float*)(LDS + 17408);          // 768 B
    _Float16* Sf = (_Float16*)(LDS + 32768);      // 8192 B

    const int g = blockIdx.x;
    const int t = threadIdx.x;

    // ---- zero S32 + cnt ----
#pragma unroll
    for (int j = 0; j < 16; ++j) S32[t + 256 * j] = 0.f;
    if (t < NPG) cnt[t] = 0;
    __syncthreads();

    // ---- edges (2/thread, live in regs all kernel) + degree count ----
    const int gb = g * NPG;
    const int i0 = t, i1 = t + 256;
    const int r0 = ei[g * EPG + i0] - gb, c0 = ei[NEDGE + g * EPG + i0] - gb;
    const int r1 = ei[g * EPG + i1] - gb, c1 = ei[NEDGE + g * EPG + i1] - gb;
    atomicAdd(&cnt[c0], 1);
    atomicAdd(&cnt[c1], 1);
    __syncthreads();

    if (t < NPG) dinvL[t] = rsqrtf((float)(cnt[t] + 1));   // +1 self loop
    __syncthreads();

    // ---- dense normalized adjacency S32[dst][src] (duplicates accumulate) ----
    atomicAdd(&S32[c0 * 64 + r0], dinvL[r0] * dinvL[c0]);
    atomicAdd(&S32[c1 * 64 + r1], dinvL[r1] * dinvL[c1]);
    if (t < NPG) atomicAdd(&S32[t * 64 + t], dinvL[t] * dinvL[t]);
    __syncthreads();

    // ---- S32 -> Sf16 (separate region), b128 writes ----
#pragma unroll
    for (int cp = 0; cp < 2; ++cp) {
        int cid = 2 * t + cp, d = cid >> 3, kc = cid & 7;
        f16x8 s8;
#pragma unroll
        for (int j = 0; j < 8; ++j) s8[j] = (_Float16)S32[d * 64 + kc * 8 + j];
        *(f16x8*)&Sf[sidx(d, kc * 8)] = s8;
    }
    __syncthreads();   // S32 reads done; Ubuf becomes H

    // ---- stage h0 = [feat | emb[nid]] as bf16 pair, b128 writes ----
#pragma unroll
    for (int rep = 0; rep < 4; ++rep) {
        int id = t + rep * 256;              // 1024 chunk tasks: n(64) x kc(16)
        int n = id >> 4, kc = id & 15;
        const float* xr = x + (g * NPG + n) * 65;
        float v[8];
        if (kc < 8) {
#pragma unroll
            for (int j = 0; j < 8; ++j) v[j] = xr[kc * 8 + j];
        } else {
            int nid = (int)xr[64];
            const float4* e4 = (const float4*)&emb[nid * DINF + (kc - 8) * 8];
            float4 va = e4[0], vb = e4[1];
            v[0] = va.x; v[1] = va.y; v[2] = va.z; v[3] = va.w;
            v[4] = vb.x; v[5] = vb.y; v[6] = vb.z; v[7] = vb.w;
        }
        short8b h8, l8;
#pragma unroll
        for (int j = 0; j < 8; ++j) {
            short hi, lo; split_bf16(v[j], hi, lo);
            h8[j] = hi; l8[j] = lo;
        }
        int idd = hidx(n, kc * 8);
        *(short8b*)&Hh[idd] = h8;
        *(short8b*)&Hl[idd] = l8;
    }
    __syncthreads();

    gcn_layer_mix(Hh, Hl, Sf, wt,         wt + 16384, b1, t);
    gcn_layer_mix(Hh, Hl, Sf, wt + 32768, wt + 49152, b2, t);
    gcn_layer_mix(Hh, Hl, Sf, wt + 65536, wt + 81920, b3, t);

    // ---- fc: gelu(h3 @ fcW + fcb) -> fcout[64][68] fp32 ----
    {
        const short* Fh = wt + 98304;
        const short* Fl = wt + 106496;
        const int l15 = t & 15, lk = (t >> 4) & 3, w = t >> 6;
        const int nb2 = w * 16;
        f32x4 fa[4];
#pragma unroll
        for (int mt = 0; mt < 4; ++mt) fa[mt] = (f32x4){0.f, 0.f, 0.f, 0.f};
        __builtin_amdgcn_s_setprio(1);
#pragma unroll
        for (int k0 = 0; k0 < 128; k0 += 32) {
            const int kk = k0 + lk * 8;
            int n = nb2 + l15;
            short8b bhf = *(const short8b*)&Fh[n * 128 + kk];
            short8b blf = *(const short8b*)&Fl[n * 128 + kk];
#pragma unroll
            for (int mt = 0; mt < 4; ++mt) {
                short8b ah = *(const short8b*)&Hh[hidx(mt * 16 + l15, kk)];
                short8b al = *(const short8b*)&Hl[hidx(mt * 16 + l15, kk)];
                fa[mt] = __builtin_amdgcn_mfma_f32_16x16x32_bf16(ah, bhf, fa[mt], 0, 0, 0);
                fa[mt] = __builtin_amdgcn_mfma_f32_16x16x32_bf16(ah, blf, fa[mt], 0, 0, 0);
                fa[mt] = __builtin_amdgcn_mfma_f32_16x16x32_bf16(al, bhf, fa[mt], 0, 0, 0);
            }
        }
        __builtin_amdgcn_s_setprio(0);
        __syncthreads();   // h3 reads done; region becomes fcout + wih
        int n = nb2 + l15;
        float fb = fcb[n];
#pragma unroll
        for (int mt = 0; mt < 4; ++mt)
#pragma unroll
            for (int r = 0; r < 4; ++r) {
                int m = mt * 16 + lk * 4 + r;
                fcout[m * 68 + n] = gelu_exact(fa[mt][r] + fb);
            }
        if (t < 3 * DINF) wihL[t] = Wih[t];
    }
    __syncthreads();

    // ---- per-edge GRU gate constants (float4 path), pre-scaled for the scan ----
    {
        const float L2E = 1.4426950408889634f;
        const float bi0 = bih[0], bi1 = bih[1], bi2 = bih[2];
        const float bh0 = bhh[0], bh1 = bhh[1];
        const float4* hra = (const float4*)&fcout[r0 * 68];
        const float4* hca = (const float4*)&fcout[c0 * 68];
        const float4* hrb = (const float4*)&fcout[r1 * 68];
        const float4* hcb = (const float4*)&fcout[c1 * 68];
        float4 ar0 = {0,0,0,0}, az0 = {0,0,0,0}, an0 = {0,0,0,0};
        float4 ar1 = {0,0,0,0}, az1 = {0,0,0,0}, an1 = {0,0,0,0};
#pragma unroll
        for (int i = 0; i < 16; ++i) {
            float4 wr = *(const float4*)&wihL[i * 4];
            float4 wz = *(const float4*)&wihL[DINF + i * 4];
            float4 wn = *(const float4*)&wihL[2 * DINF + i * 4];
            float4 pa = hra[i], qa = hca[i], pb = hrb[i], qb = hcb[i];
            float4 x0, x1;
            x0.x = 0.5f * (pa.x + qa.x); x0.y = 0.5f * (pa.y + qa.y);
            x0.z = 0.5f * (pa.z + qa.z); x0.w = 0.5f * (pa.w + qa.w);
            x1.x = 0.5f * (pb.x + qb.x); x1.y = 0.5f * (pb.y + qb.y);
            x1.z = 0.5f * (pb.z + qb.z); x1.w = 0.5f * (pb.w + qb.w);
            ar0.x = fmaf(x0.x, wr.x, ar0.x); ar0.y = fmaf(x0.y, wr.y, ar0.y);
            ar0.z = fmaf(x0.z, wr.z, ar0.z); ar0.w = fmaf(x0.w, wr.w, ar0.w);
            az0.x = fmaf(x0.x, wz.x, az0.x); az0.y = fmaf(x0.y, wz.y, az0.y);
            az0.z = fmaf(x0.z, wz.z, az0.z); az0.w = fmaf(x0.w, wz.w, az0.w);
            an0.x = fmaf(x0.x, wn.x, an0.x); an0.y = fmaf(x0.y, wn.y, an0.y);
            an0.z = fmaf(x0.z, wn.z, an0.z); an0.w = fmaf(x0.w, wn.w, an0.w);
            ar1.x = fmaf(x1.x, wr.x, ar1.x); ar1.y = fmaf(x1.y, wr.y, ar1.y);
            ar1.z = fmaf(x1.z, wr.z, ar1.z); ar1.w = fmaf(x1.w, wr.w, ar1.w);
            az1.x = fmaf(x1.x, wz.x, az1.x); az1.y = fmaf(x1.y, wz.y, az1.y);
            az1.z = fmaf(x1.z, wz.z, az1.z); az1.w = fmaf(x1.w, wz.w, az1.w);
            an1.x = fmaf(x1.x, wn.x, an1.x); an1.y = fmaf(x1.y, wn.y, an1.y);
            an1.z = fmaf(x1.z, wn.z, an1.z); an1.w = fmaf(x1.w, wn.w, an1.w);
        }
        float a0 = (ar0.x + ar0.y) + (ar0.z + ar0.w);
        float a1 = (az0.x + az0.y) + (az0.z + az0.w);
        float a2v = (an0.x + an0.y) + (an0.z + an0.w);
        size_t p = (size_t)g * EPG + i0;
        grc[p] = -L2E * (a0 + bi0 + bh0);
        gzc[p] = -L2E * (a1 + bi1 + bh1);
        gnc[p] = 2.f * L2E * (a2v + bi2);
        a0 = (ar1.x + ar1.y) + (ar1.z + ar1.w);
        a1 = (az1.x + az1.y) + (az1.z + az1.w);
        a2v = (an1.x + an1.y) + (an1.z + an1.w);
        p = (size_t)g * EPG + i1;
        grc[p] = -L2E * (a0 + bi0 + bh0);
        gzc[p] = -L2E * (a1 + bi1 + bh1);
        gnc[p] = 2.f * L2E * (a2v + bi2);
    }
}

// ---- weight pre-transpose/convert: W[k][n] -> Wt_hi/lo[n][k] bf16 ----
__global__ __launch_bounds__(256) void conv_weights(
    const float* __restrict__ W1, const float* __restrict__ W2,
    const float* __restrict__ W3, const float* __restrict__ fcW,
    short* __restrict__ wt)
{
    int tid = blockIdx.x * 256 + threadIdx.x;
    if (tid < 49152) {
        int L = tid >> 14, e = tid & 16383;
        const float* W = (L == 0) ? W1 : (L == 1) ? W2 : W3;
        float v = W[e];                  // e = k*128 + n
        int k = e >> 7, n = e & 127;
        short hi, lo; split_bf16(v, hi, lo);
        wt[L * 32768 + n * 128 + k] = hi;
        wt[L * 32768 + 16384 + n * 128 + k] = lo;
    } else if (tid < 57344) {
        int e = tid - 49152;
        float v = fcW[e];                // e = k*64 + n
        int k = e >> 6, n = e & 63;
        short hi, lo; split_bf16(v, hi, lo);
        wt[98304 + n * 128 + k] = hi;
        wt[106496 + n * 128 + k] = lo;
    }
}

// ---- repack: 3 edge-major planes -> one interleaved float4 stream.
// Reads 4B coalesced x3, writes 16B coalesced. Pure streaming (~16MB).
__global__ __launch_bounds__(256) void repack_gi(
    const float* __restrict__ grc, const float* __restrict__ gzc,
    const float* __restrict__ gnc, float4* __restrict__ gi4)
{
    int idx = blockIdx.x * 256 + threadIdx.x;   // 0..NEDGE-1, edge-major
    gi4[idx] = make_float4(grc[idx], gzc[idx], gnc[idx], 0.f);
}

// ---- GRU scan: 16 blocks x 64 threads, 1 graph/thread.
// Interleaved float4 stream (R1-proven layout: 1 load/step), depth-8
// named-register prefetch, trimmed bookkeeping (ssum>0 implies a nonzero
// exists, so lastidx is redundant).
__device__ __forceinline__ float gru_step(float h, float4 gi,
    float wrc, float wzc, float wnc2, float bnc2)
{
    float ur = fmaf(h, wrc, gi.x);
    float uz = fmaf(h, wzc, gi.y);
    float hn = fmaf(h, wnc2, bnc2);
    float rr = __builtin_amdgcn_rcpf(1.f + __builtin_amdgcn_exp2f(ur));
    float zz = __builtin_amdgcn_rcpf(1.f + __builtin_amdgcn_exp2f(uz));
    float xn = fmaf(rr, hn, gi.z);
    float qq = __builtin_amdgcn_rcpf(1.f + __builtin_amdgcn_exp2f(xn));
    float A = 1.f - zz;
    float C = fmaf(zz, h, A);
    return fmaf(qq, -2.f * A, C);   // (1-2q)(1-z) + z*h
}

__global__ __launch_bounds__(64) void gru_scan(
    const float4* __restrict__ gi4,
    const float* __restrict__ Whh, const float* __restrict__ bhh,
    const float* __restrict__ init_hs, float* __restrict__ out)
{
    const int g = blockIdx.x * 64 + threadIdx.x;
    const float L2E = 1.4426950408889634f;
    const float wrc = -L2E * Whh[0];
    const float wzc = -L2E * Whh[1];
    const float wnc2 = 2.f * L2E * Whh[2];
    const float bnc2 = 2.f * L2E * bhh[2];
    const float4* gp = gi4 + (size_t)g * EPG;
    float* flat = out + NG + (size_t)g * EPG;

    float h = init_hs[0];
    float ssum = 0.f, lastval = 0.f, firstval = 0.f;

    float4 c0 = gp[0], c1 = gp[1], c2 = gp[2], c3 = gp[3];
    float4 c4 = gp[4], c5 = gp[5], c6 = gp[6], c7 = gp[7];

    for (int tt = 0; tt < EPG; tt += 8) {
        float4 p0, p1, p2, p3, p4, p5, p6, p7;
        if (tt + 8 < EPG) {
            p0 = gp[tt + 8];  p1 = gp[tt + 9];
            p2 = gp[tt + 10]; p3 = gp[tt + 11];
            p4 = gp[tt + 12]; p5 = gp[tt + 13];
            p6 = gp[tt + 14]; p7 = gp[tt + 15];
        } else {
            p0 = c0; p1 = c1; p2 = c2; p3 = c3;
            p4 = c4; p5 = c5; p6 = c6; p7 = c7;
        }
        float4 hqa, hqb;
        h = gru_step(h, c0, wrc, wzc, wnc2, bnc2); hqa.x = h;
        h = gru_step(h, c1, wrc, wzc, wnc2, bnc2); hqa.y = h;
        h = gru_step(h, c2, wrc, wzc, wnc2, bnc2); hqa.z = h;
        h = gru_step(h, c3, wrc, wzc, wnc2, bnc2); hqa.w = h;
        h = gru_step(h, c4, wrc, wzc, wnc2, bnc2); hqb.x = h;
        h = gru_step(h, c5, wrc, wzc, wnc2, bnc2); hqb.y = h;
        h = gru_step(h, c6, wrc, wzc, wnc2, bnc2); hqb.z = h;
        h = gru_step(h, c7, wrc, wzc, wnc2, bnc2); hqb.w = h;
        *(float4*)&flat[tt] = hqa;
        *(float4*)&flat[tt + 4] = hqb;
        if (tt == 0) firstval = hqa.x;
        ssum += ((hqa.x + hqa.y) + (hqa.z + hqa.w));
        ssum += ((hqb.x + hqb.y) + (hqb.z + hqb.w));
        if (hqa.x != 0.f) lastval = hqa.x;
        if (hqa.y != 0.f) lastval = hqa.y;
        if (hqa.z != 0.f) lastval = hqa.z;
        if (hqa.w != 0.f) lastval = hqa.w;
        if (hqb.x != 0.f) lastval = hqb.x;
        if (hqb.y != 0.f) lastval = hqb.y;
        if (hqb.z != 0.f) lastval = hqb.z;
        if (hqb.w != 0.f) lastval = hqb.w;
        c0 = p0; c1 = p1; c2 = p2; c3 = p3;
        c4 = p4; c5 = p5; c6 = p6; c7 = p7;
    }
    // ssum > 0 implies at least one h != 0, so lastval is the last nonzero.
    out[g] = (ssum > 0.f) ? lastval : firstval;
}

extern "C" void kernel_launch(void* const* d_in, const int* in_sizes, int n_in,
                              void* d_out, int out_size, void* d_ws, size_t ws_size,
                              hipStream_t stream) {
    const float* x    = (const float*)d_in[0];
    const float* emb  = (const float*)d_in[1];
    const float* W1   = (const float*)d_in[2];
    const float* b1   = (const float*)d_in[3];
    const float* W2   = (const float*)d_in[4];
    const float* b2   = (const float*)d_in[5];
    const float* W3   = (const float*)d_in[6];
    const float* b3   = (const float*)d_in[7];
    const float* fcW  = (const float*)d_in[8];
    const float* fcb  = (const float*)d_in[9];
    const float* Wih  = (const float*)d_in[10];
    const float* Whh  = (const float*)d_in[11];
    const float* bih  = (const float*)d_in[12];
    const float* bhh  = (const float*)d_in[13];
    const float* ihs  = (const float*)d_in[14];
    const int*   ei   = (const int*)d_in[15];
    float* out = (float*)d_out;

    // ws: grc/gzc/gnc [0,6MB) | gi4 [6MB,14MB) | wt [14MB,+224KB)
    float*  grc = (float*)d_ws;
    float*  gzc = (float*)((char*)d_ws + (2u << 20));
    float*  gnc = (float*)((char*)d_ws + (4u << 20));
    float4* gi4 = (float4*)((char*)d_ws + (6u << 20));
    short*  wt  = (short*)((char*)d_ws + (14u << 20));

    conv_weights<<<dim3(224), dim3(256), 0, stream>>>(W1, W2, W3, fcW, wt);
    fused_graph<<<dim3(NG), dim3(256), 0, stream>>>(
        x, emb, b1, b2, b3, fcb, Wih, bih, bhh, ei, wt, grc, gzc, gnc);
    repack_gi<<<dim3(2048), dim3(256), 0, stream>>>(grc, gzc, gnc, gi4);
    gru_scan<<<dim3(16), dim3(64), 0, stream>>>(gi4, Whh, bhh, ihs, out);
}

// Round 18
// 88.495 us; speedup vs baseline: 2.0995x; 1.1844x over previous
//
#include <hip/hip_runtime.h>
#include <math.h>

#define NG    1024
#define NPG   64
#define EPG   512
#define NEDGE 524288
#define DINF  64

typedef __attribute__((ext_vector_type(8))) short short8b;     // 8 x bf16
typedef __attribute__((ext_vector_type(4))) short short4b;     // 4 x bf16
typedef __attribute__((ext_vector_type(8))) _Float16 f16x8;
typedef __attribute__((ext_vector_type(4))) _Float16 f16x4;
typedef __attribute__((ext_vector_type(4))) float f32x4;

__device__ __forceinline__ float gelu_exact(float v) {
    return 0.5f * v * (1.0f + erff(v * 0.70710678118654752440f));
}
__device__ __forceinline__ void split_bf16(float v, short& hi, short& lo) {
    unsigned u = __builtin_bit_cast(unsigned, v);
    hi = (short)(u >> 16);
    float hif = __builtin_bit_cast(float, u & 0xffff0000u);
    lo = (short)(__builtin_bit_cast(unsigned, v - hif) >> 16);
}

// ---- LDS layouts (element index), 8-elem(16B)-chunk XOR-swizzled ----
__device__ __forceinline__ int hidx(int m, int k) {   // h[64 node][128 feat] bf16-pair
    return m * 128 + (((k >> 3) ^ (m & 15)) << 3) + (k & 7);
}
__device__ __forceinline__ int tidx(int f, int m) {   // hwT[128 feat][64 node] f16-pair
    return f * 64 + (((m >> 3) ^ (f & 7)) << 3) + (m & 7);
}
__device__ __forceinline__ int sidx(int d, int k) {   // S[64 dst][64 src] f16
    return d * 64 + (((k >> 3) ^ (d & 7)) << 3) + (k & 7);
}

// One GCN layer: bf16-pair GEMM (3 products, 1 accumulator) ->
// hwT f16-pair (unscaled lo, 1 accumulator AGG) -> gelu -> bf16-pair h.
__device__ __forceinline__ void gcn_layer_mix(
    short* Hh, short* Hl, const _Float16* Sf,
    const short* __restrict__ Wh, const short* __restrict__ Wl,
    const float* __restrict__ bb, int t)
{
    const int l15 = t & 15, lk = (t >> 4) & 3, w = t >> 6;
    const int nb = w * 32;          // wave owns feats [nb, nb+32)

    // ---- GEMM: hw[node][feat] = h @ W  (M=64, N=128 (32/wave), K=128) ----
    f32x4 acc[4][2];
#pragma unroll
    for (int mt = 0; mt < 4; ++mt)
#pragma unroll
        for (int nt = 0; nt < 2; ++nt) acc[mt][nt] = (f32x4){0.f, 0.f, 0.f, 0.f};

    __builtin_amdgcn_s_setprio(1);
#pragma unroll
    for (int k0 = 0; k0 < 128; k0 += 32) {
        const int kk = k0 + lk * 8;
        short8b bh[2], bl[2];
#pragma unroll
        for (int nt = 0; nt < 2; ++nt) {
            int n = nb + nt * 16 + l15;
            bh[nt] = *(const short8b*)&Wh[n * 128 + kk];
            bl[nt] = *(const short8b*)&Wl[n * 128 + kk];
        }
#pragma unroll
        for (int mt = 0; mt < 4; ++mt) {
            short8b ah = *(const short8b*)&Hh[hidx(mt * 16 + l15, kk)];
            short8b al = *(const short8b*)&Hl[hidx(mt * 16 + l15, kk)];
#pragma unroll
            for (int nt = 0; nt < 2; ++nt) {
                acc[mt][nt] = __builtin_amdgcn_mfma_f32_16x16x32_bf16(ah, bh[nt], acc[mt][nt], 0, 0, 0);
                acc[mt][nt] = __builtin_amdgcn_mfma_f32_16x16x32_bf16(ah, bl[nt], acc[mt][nt], 0, 0, 0);
                acc[mt][nt] = __builtin_amdgcn_mfma_f32_16x16x32_bf16(al, bh[nt], acc[mt][nt], 0, 0, 0);
            }
        }
    }
    __builtin_amdgcn_s_setprio(0);
    __syncthreads();   // all waves done reading h; region becomes hwT (f16)

    _Float16* Th = (_Float16*)Hh;
    _Float16* Tl = (_Float16*)Hl;

    // ---- hwT[feat][node] f16 pair (lo unscaled), b64 writes ----
#pragma unroll
    for (int mt = 0; mt < 4; ++mt)
#pragma unroll
        for (int nt = 0; nt < 2; ++nt) {
            int f = nb + nt * 16 + l15;
            f16x4 h4, l4;
#pragma unroll
            for (int r = 0; r < 4; ++r) {
                float v = acc[mt][nt][r];
                _Float16 hi = (_Float16)v;
                _Float16 lo = (_Float16)(v - (float)hi);
                h4[r] = hi; l4[r] = lo;
            }
            int id = tidx(f, mt * 16 + lk * 4);
            *(f16x4*)&Th[id] = h4;
            *(f16x4*)&Tl[id] = l4;
        }

    // ---- AGG: D2[feat][dst] = hwT @ S^T (M=128 (32/wave), N=64, K=64) ----
    f32x4 a2[2][4];
#pragma unroll
    for (int mt = 0; mt < 2; ++mt)
#pragma unroll
        for (int nt = 0; nt < 4; ++nt) a2[mt][nt] = (f32x4){0.f, 0.f, 0.f, 0.f};

    __builtin_amdgcn_s_setprio(1);
#pragma unroll
    for (int k0 = 0; k0 < 64; k0 += 32) {
        const int kk = k0 + lk * 8;
        f16x8 sb[4];
#pragma unroll
        for (int nt = 0; nt < 4; ++nt)
            sb[nt] = *(const f16x8*)&Sf[sidx(nt * 16 + l15, kk)];
#pragma unroll
        for (int mt = 0; mt < 2; ++mt) {
            int f = nb + mt * 16 + l15;
            f16x8 ah = *(const f16x8*)&Th[tidx(f, kk)];
            f16x8 al = *(const f16x8*)&Tl[tidx(f, kk)];
#pragma unroll
            for (int nt = 0; nt < 4; ++nt) {
                a2[mt][nt] = __builtin_amdgcn_mfma_f32_16x16x32_f16(ah, sb[nt], a2[mt][nt], 0, 0, 0);
                a2[mt][nt] = __builtin_amdgcn_mfma_f32_16x16x32_f16(al, sb[nt], a2[mt][nt], 0, 0, 0);
            }
        }
    }
    __builtin_amdgcn_s_setprio(0);
    __syncthreads();   // all hwT/S reads done; region becomes new h (bf16)

    // ---- new h[node][feat] = gelu(D2^T + b[feat]); b64 (4 consecutive feats) ----
#pragma unroll
    for (int mt = 0; mt < 2; ++mt) {
        int f0 = nb + mt * 16 + lk * 4;
        float4 bv = *(const float4*)&bb[f0];
#pragma unroll
        for (int nt = 0; nt < 4; ++nt) {
            int dst = nt * 16 + l15;
            short4b h4, l4;
            float v0 = gelu_exact(a2[mt][nt][0] + bv.x);
            float v1 = gelu_exact(a2[mt][nt][1] + bv.y);
            float v2 = gelu_exact(a2[mt][nt][2] + bv.z);
            float v3 = gelu_exact(a2[mt][nt][3] + bv.w);
            short hi, lo;
            split_bf16(v0, hi, lo); h4[0] = hi; l4[0] = lo;
            split_bf16(v1, hi, lo); h4[1] = hi; l4[1] = lo;
            split_bf16(v2, hi, lo); h4[2] = hi; l4[2] = lo;
            split_bf16(v3, hi, lo); h4[3] = hi; l4[3] = lo;
            int id = hidx(dst, f0);
            *(short4b*)&Hh[id] = h4;
            *(short4b*)&Hl[id] = l4;
        }
    }
    __syncthreads();
}

__global__ __launch_bounds__(256, 4) void fused_graph(
    const float* __restrict__ x, const float* __restrict__ emb,
    const float* __restrict__ b1, const float* __restrict__ b2,
    const float* __restrict__ b3, const float* __restrict__ fcb,
    const float* __restrict__ Wih, const float* __restrict__ bih,
    const float* __restrict__ bhh,
    const int* __restrict__ ei, const short* __restrict__ wt,
    float* __restrict__ grc, float* __restrict__ gzc, float* __restrict__ gnc)
{
    // 40960 B total = 4 blocks/CU exactly; grid 1024 = one full round.
    __shared__ __align__(16) char LDS[40960];
    short* Hh = (short*)LDS;
    short* Hl = (short*)(LDS + 16384);
    float* S32 = (float*)LDS;                     // [0, 16384)
    int* cnt = (int*)(LDS + 16384);               // 256 B
    float* dinvL = (float*)(LDS + 16640);         // 256 B
    float* fcout = (float*)LDS;                   // [0, 17408)
    float* wihL = (float*)(LDS + 17408);          // 768 B
    _Float16* Sf = (_Float16*)(LDS + 32768);      // 8192 B

    const int g = blockIdx.x;
    const int t = threadIdx.x;

    // ---- zero S32 + cnt ----
#pragma unroll
    for (int j = 0; j < 16; ++j) S32[t + 256 * j] = 0.f;
    if (t < NPG) cnt[t] = 0;
    __syncthreads();

    // ---- edges (2/thread, live in regs all kernel) + degree count ----
    const int gb = g * NPG;
    const int i0 = t, i1 = t + 256;
    const int r0 = ei[g * EPG + i0] - gb, c0 = ei[NEDGE + g * EPG + i0] - gb;
    const int r1 = ei[g * EPG + i1] - gb, c1 = ei[NEDGE + g * EPG + i1] - gb;
    atomicAdd(&cnt[c0], 1);
    atomicAdd(&cnt[c1], 1);
    __syncthreads();

    if (t < NPG) dinvL[t] = rsqrtf((float)(cnt[t] + 1));   // +1 self loop
    __syncthreads();

    // ---- dense normalized adjacency S32[dst][src] (duplicates accumulate) ----
    atomicAdd(&S32[c0 * 64 + r0], dinvL[r0] * dinvL[c0]);
    atomicAdd(&S32[c1 * 64 + r1], dinvL[r1] * dinvL[c1]);
    if (t < NPG) atomicAdd(&S32[t * 64 + t], dinvL[t] * dinvL[t]);
    __syncthreads();

    // ---- S32 -> Sf16 (separate region), b128 writes ----
#pragma unroll
    for (int cp = 0; cp < 2; ++cp) {
        int cid = 2 * t + cp, d = cid >> 3, kc = cid & 7;
        f16x8 s8;
#pragma unroll
        for (int j = 0; j < 8; ++j) s8[j] = (_Float16)S32[d * 64 + kc * 8 + j];
        *(f16x8*)&Sf[sidx(d, kc * 8)] = s8;
    }
    __syncthreads();   // S32 reads done; Ubuf becomes H

    // ---- stage h0 = [feat | emb[nid]] as bf16 pair, b128 writes ----
#pragma unroll
    for (int rep = 0; rep < 4; ++rep) {
        int id = t + rep * 256;              // 1024 chunk tasks: n(64) x kc(16)
        int n = id >> 4, kc = id & 15;
        const float* xr = x + (g * NPG + n) * 65;
        float v[8];
        if (kc < 8) {
#pragma unroll
            for (int j = 0; j < 8; ++j) v[j] = xr[kc * 8 + j];
        } else {
            int nid = (int)xr[64];
            const float4* e4 = (const float4*)&emb[nid * DINF + (kc - 8) * 8];
            float4 va = e4[0], vb = e4[1];
            v[0] = va.x; v[1] = va.y; v[2] = va.z; v[3] = va.w;
            v[4] = vb.x; v[5] = vb.y; v[6] = vb.z; v[7] = vb.w;
        }
        short8b h8, l8;
#pragma unroll
        for (int j = 0; j < 8; ++j) {
            short hi, lo; split_bf16(v[j], hi, lo);
            h8[j] = hi; l8[j] = lo;
        }
        int idd = hidx(n, kc * 8);
        *(short8b*)&Hh[idd] = h8;
        *(short8b*)&Hl[idd] = l8;
    }
    __syncthreads();

    gcn_layer_mix(Hh, Hl, Sf, wt,         wt + 16384, b1, t);
    gcn_layer_mix(Hh, Hl, Sf, wt + 32768, wt + 49152, b2, t);
    gcn_layer_mix(Hh, Hl, Sf, wt + 65536, wt + 81920, b3, t);

    // ---- fc: gelu(h3 @ fcW + fcb) -> fcout[64][68] fp32 ----
    {
        const short* Fh = wt + 98304;
        const short* Fl = wt + 106496;
        const int l15 = t & 15, lk = (t >> 4) & 3, w = t >> 6;
        const int nb2 = w * 16;
        f32x4 fa[4];
#pragma unroll
        for (int mt = 0; mt < 4; ++mt) fa[mt] = (f32x4){0.f, 0.f, 0.f, 0.f};
        __builtin_amdgcn_s_setprio(1);
#pragma unroll
        for (int k0 = 0; k0 < 128; k0 += 32) {
            const int kk = k0 + lk * 8;
            int n = nb2 + l15;
            short8b bhf = *(const short8b*)&Fh[n * 128 + kk];
            short8b blf = *(const short8b*)&Fl[n * 128 + kk];
#pragma unroll
            for (int mt = 0; mt < 4; ++mt) {
                short8b ah = *(const short8b*)&Hh[hidx(mt * 16 + l15, kk)];
                short8b al = *(const short8b*)&Hl[hidx(mt * 16 + l15, kk)];
                fa[mt] = __builtin_amdgcn_mfma_f32_16x16x32_bf16(ah, bhf, fa[mt], 0, 0, 0);
                fa[mt] = __builtin_amdgcn_mfma_f32_16x16x32_bf16(ah, blf, fa[mt], 0, 0, 0);
                fa[mt] = __builtin_amdgcn_mfma_f32_16x16x32_bf16(al, bhf, fa[mt], 0, 0, 0);
            }
        }
        __builtin_amdgcn_s_setprio(0);
        __syncthreads();   // h3 reads done; region becomes fcout + wih
        int n = nb2 + l15;
        float fb = fcb[n];
#pragma unroll
        for (int mt = 0; mt < 4; ++mt)
#pragma unroll
            for (int r = 0; r < 4; ++r) {
                int m = mt * 16 + lk * 4 + r;
                fcout[m * 68 + n] = gelu_exact(fa[mt][r] + fb);
            }
        if (t < 3 * DINF) wihL[t] = Wih[t];
    }
    __syncthreads();

    // ---- per-edge GRU gate constants (float4 path), pre-scaled for the scan ----
    {
        const float L2E = 1.4426950408889634f;
        const float bi0 = bih[0], bi1 = bih[1], bi2 = bih[2];
        const float bh0 = bhh[0], bh1 = bhh[1];
        const float4* hra = (const float4*)&fcout[r0 * 68];
        const float4* hca = (const float4*)&fcout[c0 * 68];
        const float4* hrb = (const float4*)&fcout[r1 * 68];
        const float4* hcb = (const float4*)&fcout[c1 * 68];
        float4 ar0 = {0,0,0,0}, az0 = {0,0,0,0}, an0 = {0,0,0,0};
        float4 ar1 = {0,0,0,0}, az1 = {0,0,0,0}, an1 = {0,0,0,0};
#pragma unroll
        for (int i = 0; i < 16; ++i) {
            float4 wr = *(const float4*)&wihL[i * 4];
            float4 wz = *(const float4*)&wihL[DINF + i * 4];
            float4 wn = *(const float4*)&wihL[2 * DINF + i * 4];
            float4 pa = hra[i], qa = hca[i], pb = hrb[i], qb = hcb[i];
            float4 x0, x1;
            x0.x = 0.5f * (pa.x + qa.x); x0.y = 0.5f * (pa.y + qa.y);
            x0.z = 0.5f * (pa.z + qa.z); x0.w = 0.5f * (pa.w + qa.w);
            x1.x = 0.5f * (pb.x + qb.x); x1.y = 0.5f * (pb.y + qb.y);
            x1.z = 0.5f * (pb.z + qb.z); x1.w = 0.5f * (pb.w + qb.w);
            ar0.x = fmaf(x0.x, wr.x, ar0.x); ar0.y = fmaf(x0.y, wr.y, ar0.y);
            ar0.z = fmaf(x0.z, wr.z, ar0.z); ar0.w = fmaf(x0.w, wr.w, ar0.w);
            az0.x = fmaf(x0.x, wz.x, az0.x); az0.y = fmaf(x0.y, wz.y, az0.y);
            az0.z = fmaf(x0.z, wz.z, az0.z); az0.w = fmaf(x0.w, wz.w, az0.w);
            an0.x = fmaf(x0.x, wn.x, an0.x); an0.y = fmaf(x0.y, wn.y, an0.y);
            an0.z = fmaf(x0.z, wn.z, an0.z); an0.w = fmaf(x0.w, wn.w, an0.w);
            ar1.x = fmaf(x1.x, wr.x, ar1.x); ar1.y = fmaf(x1.y, wr.y, ar1.y);
            ar1.z = fmaf(x1.z, wr.z, ar1.z); ar1.w = fmaf(x1.w, wr.w, ar1.w);
            az1.x = fmaf(x1.x, wz.x, az1.x); az1.y = fmaf(x1.y, wz.y, az1.y);
            az1.z = fmaf(x1.z, wz.z, az1.z); az1.w = fmaf(x1.w, wz.w, az1.w);
            an1.x = fmaf(x1.x, wn.x, an1.x); an1.y = fmaf(x1.y, wn.y, an1.y);
            an1.z = fmaf(x1.z, wn.z, an1.z); an1.w = fmaf(x1.w, wn.w, an1.w);
        }
        float a0 = (ar0.x + ar0.y) + (ar0.z + ar0.w);
        float a1 = (az0.x + az0.y) + (az0.z + az0.w);
        float a2v = (an0.x + an0.y) + (an0.z + an0.w);
        size_t p = (size_t)g * EPG + i0;
        grc[p] = -L2E * (a0 + bi0 + bh0);
        gzc[p] = -L2E * (a1 + bi1 + bh1);
        gnc[p] = 2.f * L2E * (a2v + bi2);
        a0 = (ar1.x + ar1.y) + (ar1.z + ar1.w);
        a1 = (az1.x + az1.y) + (az1.z + az1.w);
        a2v = (an1.x + an1.y) + (an1.z + an1.w);
        p = (size_t)g * EPG + i1;
        grc[p] = -L2E * (a0 + bi0 + bh0);
        gzc[p] = -L2E * (a1 + bi1 + bh1);
        gnc[p] = 2.f * L2E * (a2v + bi2);
    }
}

// ---- weight pre-transpose/convert: W[k][n] -> Wt_hi/lo[n][k] bf16 ----
__global__ __launch_bounds__(256) void conv_weights(
    const float* __restrict__ W1, const float* __restrict__ W2,
    const float* __restrict__ W3, const float* __restrict__ fcW,
    short* __restrict__ wt)
{
    int tid = blockIdx.x * 256 + threadIdx.x;
    if (tid < 49152) {
        int L = tid >> 14, e = tid & 16383;
        const float* W = (L == 0) ? W1 : (L == 1) ? W2 : W3;
        float v = W[e];                  // e = k*128 + n
        int k = e >> 7, n = e & 127;
        short hi, lo; split_bf16(v, hi, lo);
        wt[L * 32768 + n * 128 + k] = hi;
        wt[L * 32768 + 16384 + n * 128 + k] = lo;
    } else if (tid < 57344) {
        int e = tid - 49152;
        float v = fcW[e];                // e = k*64 + n
        int k = e >> 6, n = e & 63;
        short hi, lo; split_bf16(v, hi, lo);
        wt[98304 + n * 128 + k] = hi;
        wt[106496 + n * 128 + k] = lo;
    }
}

// ---- GRU scan: 16 blocks x 64 threads, 1 graph/thread, depth-16 prefetch.
// lastidx dropped: ssum>0 implies a nonzero exists, so lastval suffices.
__device__ __forceinline__ float gru_step(float h, float gr, float gz, float gn,
    float wrc, float wzc, float wnc2, float bnc2)
{
    float ur = fmaf(h, wrc, gr);
    float uz = fmaf(h, wzc, gz);
    float hn = fmaf(h, wnc2, bnc2);
    float rr = __builtin_amdgcn_rcpf(1.f + __builtin_amdgcn_exp2f(ur));
    float zz = __builtin_amdgcn_rcpf(1.f + __builtin_amdgcn_exp2f(uz));
    float xn = fmaf(rr, hn, gn);
    float qq = __builtin_amdgcn_rcpf(1.f + __builtin_amdgcn_exp2f(xn));
    float A = 1.f - zz;
    float C = fmaf(zz, h, A);
    return fmaf(qq, -2.f * A, C);   // (1-2q)(1-z) + z*h
}

__global__ __launch_bounds__(64) void gru_scan(
    const float* __restrict__ grc, const float* __restrict__ gzc,
    const float* __restrict__ gnc,
    const float* __restrict__ Whh, const float* __restrict__ bhh,
    const float* __restrict__ init_hs, float* __restrict__ out)
{
    const int g = blockIdx.x * 64 + threadIdx.x;
    const float L2E = 1.4426950408889634f;
    const float wrc = -L2E * Whh[0];
    const float wzc = -L2E * Whh[1];
    const float wnc2 = 2.f * L2E * Whh[2];
    const float bnc2 = 2.f * L2E * bhh[2];
    const float* pr = grc + (size_t)g * EPG;
    const float* pz = gzc + (size_t)g * EPG;
    const float* pn = gnc + (size_t)g * EPG;
    float* flat = out + NG + (size_t)g * EPG;

    float h = init_hs[0];
    float ssum = 0.f, lastval = 0.f, firstval = 0.f;

    float4 r0 = *(const float4*)&pr[0],  r1 = *(const float4*)&pr[4];
    float4 r2 = *(const float4*)&pr[8],  r3 = *(const float4*)&pr[12];
    float4 z0 = *(const float4*)&pz[0],  z1 = *(const float4*)&pz[4];
    float4 z2 = *(const float4*)&pz[8],  z3 = *(const float4*)&pz[12];
    float4 n0 = *(const float4*)&pn[0],  n1 = *(const float4*)&pn[4];
    float4 n2 = *(const float4*)&pn[8],  n3 = *(const float4*)&pn[12];

    for (int tt = 0; tt < EPG; tt += 16) {
        float4 qr0, qr1, qr2, qr3, qz0, qz1, qz2, qz3, qn0, qn1, qn2, qn3;
        if (tt + 16 < EPG) {   // depth-16 prefetch, static names
            qr0 = *(const float4*)&pr[tt + 16]; qr1 = *(const float4*)&pr[tt + 20];
            qr2 = *(const float4*)&pr[tt + 24]; qr3 = *(const float4*)&pr[tt + 28];
            qz0 = *(const float4*)&pz[tt + 16]; qz1 = *(const float4*)&pz[tt + 20];
            qz2 = *(const float4*)&pz[tt + 24]; qz3 = *(const float4*)&pz[tt + 28];
            qn0 = *(const float4*)&pn[tt + 16]; qn1 = *(const float4*)&pn[tt + 20];
            qn2 = *(const float4*)&pn[tt + 24]; qn3 = *(const float4*)&pn[tt + 28];
        } else {
            qr0 = r0; qr1 = r1; qr2 = r2; qr3 = r3;
            qz0 = z0; qz1 = z1; qz2 = z2; qz3 = z3;
            qn0 = n0; qn1 = n1; qn2 = n2; qn3 = n3;
        }
        float4 hqa, hqb, hqc, hqd;
        h = gru_step(h, r0.x, z0.x, n0.x, wrc, wzc, wnc2, bnc2); hqa.x = h;
        h = gru_step(h, r0.y, z0.y, n0.y, wrc, wzc, wnc2, bnc2); hqa.y = h;
        h = gru_step(h, r0.z, z0.z, n0.z, wrc, wzc, wnc2, bnc2); hqa.z = h;
        h = gru_step(h, r0.w, z0.w, n0.w, wrc, wzc, wnc2, bnc2); hqa.w = h;
        h = gru_step(h, r1.x, z1.x, n1.x, wrc, wzc, wnc2, bnc2); hqb.x = h;
        h = gru_step(h, r1.y, z1.y, n1.y, wrc, wzc, wnc2, bnc2); hqb.y = h;
        h = gru_step(h, r1.z, z1.z, n1.z, wrc, wzc, wnc2, bnc2); hqb.z = h;
        h = gru_step(h, r1.w, z1.w, n1.w, wrc, wzc, wnc2, bnc2); hqb.w = h;
        h = gru_step(h, r2.x, z2.x, n2.x, wrc, wzc, wnc2, bnc2); hqc.x = h;
        h = gru_step(h, r2.y, z2.y, n2.y, wrc, wzc, wnc2, bnc2); hqc.y = h;
        h = gru_step(h, r2.z, z2.z, n2.z, wrc, wzc, wnc2, bnc2); hqc.z = h;
        h = gru_step(h, r2.w, z2.w, n2.w, wrc, wzc, wnc2, bnc2); hqc.w = h;
        h = gru_step(h, r3.x, z3.x, n3.x, wrc, wzc, wnc2, bnc2); hqd.x = h;
        h = gru_step(h, r3.y, z3.y, n3.y, wrc, wzc, wnc2, bnc2); hqd.y = h;
        h = gru_step(h, r3.z, z3.z, n3.z, wrc, wzc, wnc2, bnc2); hqd.z = h;
        h = gru_step(h, r3.w, z3.w, n3.w, wrc, wzc, wnc2, bnc2); hqd.w = h;
        *(float4*)&flat[tt] = hqa;
        *(float4*)&flat[tt + 4] = hqb;
        *(float4*)&flat[tt + 8] = hqc;
        *(float4*)&flat[tt + 12] = hqd;
        if (tt == 0) firstval = hqa.x;
        ssum += ((hqa.x + hqa.y) + (hqa.z + hqa.w));
        ssum += ((hqb.x + hqb.y) + (hqb.z + hqb.w));
        ssum += ((hqc.x + hqc.y) + (hqc.z + hqc.w));
        ssum += ((hqd.x + hqd.y) + (hqd.z + hqd.w));
        if (hqa.x != 0.f) lastval = hqa.x;
        if (hqa.y != 0.f) lastval = hqa.y;
        if (hqa.z != 0.f) lastval = hqa.z;
        if (hqa.w != 0.f) lastval = hqa.w;
        if (hqb.x != 0.f) lastval = hqb.x;
        if (hqb.y != 0.f) lastval = hqb.y;
        if (hqb.z != 0.f) lastval = hqb.z;
        if (hqb.w != 0.f) lastval = hqb.w;
        if (hqc.x != 0.f) lastval = hqc.x;
        if (hqc.y != 0.f) lastval = hqc.y;
        if (hqc.z != 0.f) lastval = hqc.z;
        if (hqc.w != 0.f) lastval = hqc.w;
        if (hqd.x != 0.f) lastval = hqd.x;
        if (hqd.y != 0.f) lastval = hqd.y;
        if (hqd.z != 0.f) lastval = hqd.z;
        if (hqd.w != 0.f) lastval = hqd.w;
        r0 = qr0; r1 = qr1; r2 = qr2; r3 = qr3;
        z0 = qz0; z1 = qz1; z2 = qz2; z3 = qz3;
        n0 = qn0; n1 = qn1; n2 = qn2; n3 = qn3;
    }
    // ssum > 0 implies at least one h != 0, so lastval is the last nonzero.
    out[g] = (ssum > 0.f) ? lastval : firstval;
}

extern "C" void kernel_launch(void* const* d_in, const int* in_sizes, int n_in,
                              void* d_out, int out_size, void* d_ws, size_t ws_size,
                              hipStream_t stream) {
    const float* x    = (const float*)d_in[0];
    const float* emb  = (const float*)d_in[1];
    const float* W1   = (const float*)d_in[2];
    const float* b1   = (const float*)d_in[3];
    const float* W2   = (const float*)d_in[4];
    const float* b2   = (const float*)d_in[5];
    const float* W3   = (const float*)d_in[6];
    const float* b3   = (const float*)d_in[7];
    const float* fcW  = (const float*)d_in[8];
    const float* fcb  = (const float*)d_in[9];
    const float* Wih  = (const float*)d_in[10];
    const float* Whh  = (const float*)d_in[11];
    const float* bih  = (const float*)d_in[12];
    const float* bhh  = (const float*)d_in[13];
    const float* ihs  = (const float*)d_in[14];
    const int*   ei   = (const int*)d_in[15];
    float* out = (float*)d_out;

    float* grc = (float*)d_ws;
    float* gzc = (float*)((char*)d_ws + (2u << 20));
    float* gnc = (float*)((char*)d_ws + (4u << 20));
    short* wt  = (short*)((char*)d_ws + (6u << 20));

    conv_weights<<<dim3(224), dim3(256), 0, stream>>>(W1, W2, W3, fcW, wt);
    fused_graph<<<dim3(NG), dim3(256), 0, stream>>>(
        x, emb, b1, b2, b3, fcb, Wih, bih, bhh, ei, wt, grc, gzc, gnc);
    gru_scan<<<dim3(16), dim3(64), 0, stream>>>(grc, gzc, gnc, Whh, bhh, ihs, out);
}